// Round 1
// baseline (500.451 us; speedup 1.0000x reference)
//
#include <hip/hip_runtime.h>
#include <hip/hip_bf16.h>

typedef short short8 __attribute__((ext_vector_type(8)));
typedef unsigned short ushort8 __attribute__((ext_vector_type(8)));
typedef float float4v __attribute__((ext_vector_type(4)));

#define NSPLIT 6
#define TK 32

__device__ __forceinline__ unsigned short f2bf(float f) {
    unsigned int u = __builtin_bit_cast(unsigned int, f);
    unsigned int r = u + 0x7fffu + ((u >> 16) & 1u);   // RNE
    return (unsigned short)(r >> 16);
}

// ---------------- K1: split-K bf16 MFMA GEMM: P_mod[b][j] = sum_k A[b,k] * W[j,k] ----------------
// 128x128 tiles, 4 waves of 64x64, BK=32, double-buffered LDS, reg-prefetch of next step.
__global__ __launch_bounds__(256, 2) void gemm_kernel(
    const float* __restrict__ Ae, const float* __restrict__ Am, const float* __restrict__ Ac,
    const float* __restrict__ Wex, const float* __restrict__ Wey,
    const float* __restrict__ Wmx, const float* __restrict__ Wmy,
    const float* __restrict__ Wcx, const float* __restrict__ Wcy,
    float* __restrict__ part)
{
    // XCD-aware swizzle: bid%8 = XCD (heuristic); 4 blocks of one 2x2 tile cluster share an XCD.
    int bid = blockIdx.x;
    int job = (bid & 7) * 36 + (bid >> 3);      // 288 jobs
    int cluster = job >> 2, within = job & 3;   // 72 clusters of 4
    int mod = cluster / 24, cm = cluster % 24;
    int split = cm >> 2, c2 = cm & 3;
    int ti = ((c2 >> 1) << 1) | (within >> 1);  // A-row tile 0..3
    int tj = ((c2 & 1) << 1) | (within & 1);    // W-row tile 0..3

    const float* A; const float* Wx; const float* Wy; int K;
    if (mod == 0)      { A = Ae; Wx = Wex; Wy = Wey; K = 20000; }
    else if (mod == 1) { A = Am; Wx = Wmx; Wy = Wmy; K = 15000; }
    else               { A = Ac; Wx = Wcx; Wy = Wcy; K = 20000; }

    int chunk = ((K + NSPLIT * TK - 1) / (NSPLIT * TK)) * TK;
    int kstart = split * chunk;
    int kend = kstart + chunk; if (kend > K) kend = K;
    int nstep = (kend - kstart + TK - 1) / TK;

    const float* Abase = A + (size_t)(ti * 128) * K;
    const float* Wbase = (tj < 2) ? (Wx + (size_t)(tj * 128) * K)
                                  : (Wy + (size_t)((tj - 2) * 128) * K);

    __shared__ unsigned short As[2][128][32];
    __shared__ unsigned short Bs[2][128][32];

    int tid = threadIdx.x;
    int arow = tid >> 1, half = tid & 1, colbase = half * 16;
    const float* arp = Abase + (size_t)arow * K;
    const float* brp = Wbase + (size_t)arow * K;

    int lane = tid & 63, w = tid >> 6;
    int wr = (w >> 1) * 64, wc = (w & 1) * 64;
    int q8 = (lane >> 4) * 8, r16 = lane & 15;

    float4v fA[4], fB[4];
    auto load_step = [&](int k0) {
        #pragma unroll
        for (int i = 0; i < 4; ++i) {
            int kk = k0 + colbase + 4 * i;
            float4v z = {0.f, 0.f, 0.f, 0.f};
            fA[i] = (kk < kend) ? *(const float4v*)(arp + kk) : z;
            fB[i] = (kk < kend) ? *(const float4v*)(brp + kk) : z;
        }
    };
    auto store_step = [&](int buf) {
        union { unsigned short s[16]; ushort8 v[2]; } ua, ub;
        #pragma unroll
        for (int i = 0; i < 4; ++i)
            #pragma unroll
            for (int c = 0; c < 4; ++c) {
                ua.s[4 * i + c] = f2bf(fA[i][c]);
                ub.s[4 * i + c] = f2bf(fB[i][c]);
            }
        *(ushort8*)&As[buf][arow][colbase]     = ua.v[0];
        *(ushort8*)&As[buf][arow][colbase + 8] = ua.v[1];
        *(ushort8*)&Bs[buf][arow][colbase]     = ub.v[0];
        *(ushort8*)&Bs[buf][arow][colbase + 8] = ub.v[1];
    };

    float4v acc[4][4];
    #pragma unroll
    for (int a = 0; a < 4; ++a)
        #pragma unroll
        for (int b = 0; b < 4; ++b)
            acc[a][b] = (float4v){0.f, 0.f, 0.f, 0.f};

    load_step(kstart);
    store_step(0);
    __syncthreads();

    for (int s = 0; s < nstep; ++s) {
        int cur = s & 1;
        bool more = (s + 1 < nstep);
        if (more) load_step(kstart + (s + 1) * TK);   // loads in flight over the MFMAs

        short8 fa[4], fb[4];
        #pragma unroll
        for (int a = 0; a < 4; ++a)
            fa[a] = *(const short8*)&As[cur][wr + a * 16 + r16][q8];
        #pragma unroll
        for (int b = 0; b < 4; ++b)
            fb[b] = *(const short8*)&Bs[cur][wc + b * 16 + r16][q8];
        #pragma unroll
        for (int a = 0; a < 4; ++a)
            #pragma unroll
            for (int b = 0; b < 4; ++b)
                acc[a][b] = __builtin_amdgcn_mfma_f32_16x16x32_bf16(fa[a], fb[b], acc[a][b], 0, 0, 0);

        if (more) store_step(cur ^ 1);
        __syncthreads();
    }

    // partial tile out: part[mod][ti][tj][split][128][128]
    float* pbase = part + (size_t)((((mod * 4 + ti) * 4 + tj) * NSPLIT) + split) * 16384;
    #pragma unroll
    for (int a = 0; a < 4; ++a)
        #pragma unroll
        for (int b = 0; b < 4; ++b)
            #pragma unroll
            for (int r = 0; r < 4; ++r) {
                int row = wr + a * 16 + (lane >> 4) * 4 + r;  // C/D: row = quad*4+reg
                int col = wc + b * 16 + r16;                   // col = lane&15
                pbase[row * 128 + col] = acc[a][b][r];
            }
}

// ---------------- K2: split-K reduction + zero head accumulators ----------------
__global__ void reduce_kernel(const float* __restrict__ part, float* __restrict__ P,
                              float* __restrict__ headacc)
{
    int gid = blockIdx.x * 256 + threadIdx.x;   // 786432 total
    if (gid < 1536) headacc[gid] = 0.f;
    int mod = gid >> 18;
    int rem = gid & 262143;
    int b = rem >> 9, j = rem & 511;
    int ti = b >> 7, r = b & 127, tj = j >> 7, c = j & 127;
    const float* src = part + (size_t)(((mod * 4 + ti) * 4 + tj) * NSPLIT) * 16384 + r * 128 + c;
    float s = 0.f;
    #pragma unroll
    for (int k = 0; k < NSPLIT; ++k) s += src[k * 16384];
    P[gid] = s;
}

// ---------------- K3: per-(batch,pair) fused normalize + rank-2 attention + head partials ----------------
__global__ __launch_bounds__(256) void pairs_kernel(
    const float* __restrict__ P, float* __restrict__ headacc,
    const float* __restrict__ W3e, const float* __restrict__ W3m, const float* __restrict__ W3c)
{
    int b = blockIdx.x / 3, pair = blockIdx.x % 3;   // 0:em 1:ec 2:mc
    int t = threadIdx.x;
    __shared__ float2 Pn[256], Qn[256];
    __shared__ float Rinv[256];
    __shared__ float red[4];

    int pm = (pair == 2) ? 1 : 0;
    int qm = (pair == 0) ? 1 : 2;
    const float* prow = P + pm * 262144 + b * 512;
    const float* qrow = P + qm * 262144 + b * 512;

    float px = prow[t], py = prow[256 + t];
    float ip = rsqrtf(px * px + py * py);
    Pn[t] = (float2){px * ip, py * ip};
    float qx = qrow[t], qy = qrow[256 + t];
    float iq = rsqrtf(qx * qx + qy * qy);
    Qn[t] = (float2){qx * iq, qy * iq};
    __syncthreads();

    const float L2E = 1.4426950408889634f;

    // ---- pass R: thread = row r. rowsum + q-weighted row sums -> B-side output (q's feature) ----
    float pxr = Pn[t].x * L2E, pyr = Pn[t].y * L2E;
    float rs = 0.f, rqx = 0.f, rqy = 0.f;
    #pragma unroll 4
    for (int j = 0; j < 256; ++j) {
        float2 qv = Qn[j];
        float x = exp2f(fmaf(pyr, qv.y, pxr * qv.x));
        rs += x;
        rqx = fmaf(qv.x, x, rqx);
        rqy = fmaf(qv.y, x, rqy);
    }
    float rinv = 1.f / rs;
    Rinv[t] = rinv;
    float Fq0 = rqx * rinv, Fq1 = rqy * rinv;

    const float* WR; int hR, offR;
    if (pair == 0)      { WR = W3m; hR = 1; offR = 0; }   // m_feat chunks 0,1
    else if (pair == 1) { WR = W3c; hR = 2; offR = 0; }   // c_feat chunks 0,1
    else                { WR = W3c; hR = 2; offR = 512; } // c_feat chunks 2,3
    float v = Fq0 * WR[offR + t] + Fq1 * WR[offR + 256 + t];
    #pragma unroll
    for (int o = 32; o > 0; o >>= 1) v += __shfl_down(v, o, 64);
    if ((t & 63) == 0) red[t >> 6] = v;
    __syncthreads();
    if (t == 0) atomicAdd(&headacc[b * 3 + hR], red[0] + red[1] + red[2] + red[3]);
    __syncthreads();

    // ---- pass C: thread = col n. col softmax (A-side) or rowsum-prescaled matmul (mc C-form) ----
    float qxr = Qn[t].x * L2E, qyr = Qn[t].y * L2E;
    float cs = 0.f, cpx = 0.f, cpy = 0.f;
    if (pair < 2) {
        #pragma unroll 4
        for (int i = 0; i < 256; ++i) {
            float2 pv = Pn[i];
            float x = exp2f(fmaf(qyr, pv.y, qxr * pv.x));
            cs += x;
            cpx = fmaf(pv.x, x, cpx);
            cpy = fmaf(pv.y, x, cpy);
        }
        float ci = 1.f / cs;
        cpx *= ci; cpy *= ci;
    } else {
        #pragma unroll 4
        for (int i = 0; i < 256; ++i) {
            float2 pv = Pn[i];
            float x = exp2f(fmaf(qyr, pv.y, qxr * pv.x)) * Rinv[i];
            cpx = fmaf(pv.x, x, cpx);
            cpy = fmaf(pv.y, x, cpy);
        }
    }
    const float* WC; int hC, offC;
    if (pair == 0)      { WC = W3e; hC = 0; offC = 0; }   // e_feat chunks 0,1
    else if (pair == 1) { WC = W3e; hC = 0; offC = 512; } // e_feat chunks 2,3
    else                { WC = W3m; hC = 1; offC = 512; } // m_feat chunks 2,3
    float v2 = cpx * WC[offC + t] + cpy * WC[offC + 256 + t];
    #pragma unroll
    for (int o = 32; o > 0; o >>= 1) v2 += __shfl_down(v2, o, 64);
    if ((t & 63) == 0) red[t >> 6] = v2;
    __syncthreads();
    if (t == 0) atomicAdd(&headacc[b * 3 + hC], red[0] + red[1] + red[2] + red[3]);
}

// ---------------- K4: bias + sigmoid ----------------
__global__ void head_kernel(const float* __restrict__ headacc,
                            const float* __restrict__ b3e, const float* __restrict__ b3m,
                            const float* __restrict__ b3c, float* __restrict__ out)
{
    int i = blockIdx.x * 256 + threadIdx.x;
    if (i >= 1536) return;
    int h = i >> 9, b = i & 511;
    float bias = (h == 0) ? b3e[0] : (h == 1) ? b3m[0] : b3c[0];
    float z = headacc[b * 3 + h] + bias;
    out[i] = 1.f / (1.f + __expf(-z));
}

extern "C" void kernel_launch(void* const* d_in, const int* in_sizes, int n_in,
                              void* d_out, int out_size, void* d_ws, size_t ws_size,
                              hipStream_t stream) {
    const float* Ae  = (const float*)d_in[0];
    const float* Am  = (const float*)d_in[1];
    const float* Ac  = (const float*)d_in[2];
    const float* Wex = (const float*)d_in[3];
    const float* Wey = (const float*)d_in[4];
    const float* Wmx = (const float*)d_in[5];
    const float* Wmy = (const float*)d_in[6];
    const float* Wcx = (const float*)d_in[7];
    const float* Wcy = (const float*)d_in[8];
    const float* W3e = (const float*)d_in[9];
    const float* b3e = (const float*)d_in[10];
    const float* W3m = (const float*)d_in[11];
    const float* b3m = (const float*)d_in[12];
    const float* W3c = (const float*)d_in[13];
    const float* b3c = (const float*)d_in[14];

    float* part    = (float*)d_ws;                 // 288 * 16384 floats = 18.9 MB
    float* P       = part + (size_t)288 * 16384;   // 3 * 512 * 512 floats = 3 MB
    float* headacc = P + 786432;                   // 1536 floats

    gemm_kernel<<<288, 256, 0, stream>>>(Ae, Am, Ac, Wex, Wey, Wmx, Wmy, Wcx, Wcy, part);
    reduce_kernel<<<3072, 256, 0, stream>>>(part, P, headacc);
    pairs_kernel<<<1536, 256, 0, stream>>>(P, headacc, W3e, W3m, W3c);
    head_kernel<<<6, 256, 0, stream>>>(headacc, b3e, b3m, b3c, (float*)d_out);
}

// Round 2
// 424.306 us; speedup vs baseline: 1.1795x; 1.1795x over previous
//
#include <hip/hip_runtime.h>
#include <hip/hip_bf16.h>

typedef short short8 __attribute__((ext_vector_type(8)));
typedef unsigned short ushort8 __attribute__((ext_vector_type(8)));
typedef float float4v __attribute__((ext_vector_type(4)));

#define TK 32
#define MAXSPLIT 16
#define LDSPAD 40   // 80 B row stride = 20 banks -> conflict-free rotation, 16B-aligned

// ---------------- K1: split-K bf16 MFMA GEMM: P_mod[b][j] = sum_k A[b,k] * W[j,k] ----------------
// 128x128 tiles, 4 waves of 64x64, BK=32, double-buffered LDS, reg-prefetch of next step.
__global__ __launch_bounds__(256, 4) void gemm_kernel(
    const float* __restrict__ Ae, const float* __restrict__ Am, const float* __restrict__ Ac,
    const float* __restrict__ Wex, const float* __restrict__ Wey,
    const float* __restrict__ Wmx, const float* __restrict__ Wmy,
    const float* __restrict__ Wcx, const float* __restrict__ Wcy,
    float* __restrict__ part, int nsplit)
{
    int job = blockIdx.x;                     // 48 * nsplit jobs
    int mod = job / (16 * nsplit);
    int rem = job - mod * 16 * nsplit;
    int split = rem >> 4;
    int t2 = rem & 15;
    int ti = t2 >> 2, tj = t2 & 3;

    const float* A; const float* Wx; const float* Wy; int K;
    if (mod == 0)      { A = Ae; Wx = Wex; Wy = Wey; K = 20000; }
    else if (mod == 1) { A = Am; Wx = Wmx; Wy = Wmy; K = 15000; }
    else               { A = Ac; Wx = Wcx; Wy = Wcy; K = 20000; }

    int chunk = ((K + nsplit * TK - 1) / (nsplit * TK)) * TK;
    int kstart = split * chunk;
    int kend = kstart + chunk; if (kend > K) kend = K;
    int nstep = (kend > kstart) ? (kend - kstart + TK - 1) / TK : 0;

    const float* Abase = A + (size_t)(ti * 128) * K;
    const float* Wbase = (tj < 2) ? (Wx + (size_t)(tj * 128) * K)
                                  : (Wy + (size_t)((tj - 2) * 128) * K);

    __shared__ unsigned short As[2][128][LDSPAD];
    __shared__ unsigned short Bs[2][128][LDSPAD];

    int tid = threadIdx.x;
    int arow = tid >> 1, half = tid & 1, colbase = half * 16;
    const float* arp = Abase + (size_t)arow * K;
    const float* brp = Wbase + (size_t)arow * K;

    int lane = tid & 63, w = tid >> 6;
    int wr = (w >> 1) * 64, wc = (w & 1) * 64;
    int q8 = (lane >> 4) * 8, r16 = lane & 15;

    float4v fA[4], fB[4];
    auto load_step = [&](int k0) {
        #pragma unroll
        for (int i = 0; i < 4; ++i) {
            int kk = k0 + colbase + 4 * i;
            float4v z = {0.f, 0.f, 0.f, 0.f};
            fA[i] = (kk < kend) ? *(const float4v*)(arp + kk) : z;
            fB[i] = (kk < kend) ? *(const float4v*)(brp + kk) : z;
        }
    };
    auto store_step = [&](int buf) {
        union { __hip_bfloat162 h[8]; ushort8 v[2]; } ua, ub;
        #pragma unroll
        for (int i = 0; i < 4; ++i) {
            ua.h[2 * i]     = __float22bfloat162_rn({fA[i][0], fA[i][1]});
            ua.h[2 * i + 1] = __float22bfloat162_rn({fA[i][2], fA[i][3]});
            ub.h[2 * i]     = __float22bfloat162_rn({fB[i][0], fB[i][1]});
            ub.h[2 * i + 1] = __float22bfloat162_rn({fB[i][2], fB[i][3]});
        }
        *(ushort8*)&As[buf][arow][colbase]     = ua.v[0];
        *(ushort8*)&As[buf][arow][colbase + 8] = ua.v[1];
        *(ushort8*)&Bs[buf][arow][colbase]     = ub.v[0];
        *(ushort8*)&Bs[buf][arow][colbase + 8] = ub.v[1];
    };

    float4v acc[4][4];
    #pragma unroll
    for (int a = 0; a < 4; ++a)
        #pragma unroll
        for (int b = 0; b < 4; ++b)
            acc[a][b] = (float4v){0.f, 0.f, 0.f, 0.f};

    if (nstep > 0) {
        load_step(kstart);
        store_step(0);
    }
    __syncthreads();

    for (int s = 0; s < nstep; ++s) {
        int cur = s & 1;
        bool more = (s + 1 < nstep);
        if (more) load_step(kstart + (s + 1) * TK);   // loads in flight over the MFMAs

        short8 fa[4], fb[4];
        #pragma unroll
        for (int a = 0; a < 4; ++a)
            fa[a] = *(const short8*)&As[cur][wr + a * 16 + r16][q8];
        #pragma unroll
        for (int b = 0; b < 4; ++b)
            fb[b] = *(const short8*)&Bs[cur][wc + b * 16 + r16][q8];
        #pragma unroll
        for (int a = 0; a < 4; ++a)
            #pragma unroll
            for (int b = 0; b < 4; ++b)
                acc[a][b] = __builtin_amdgcn_mfma_f32_16x16x32_bf16(fa[a], fb[b], acc[a][b], 0, 0, 0);

        if (more) store_step(cur ^ 1);
        __syncthreads();
    }

    // partial tile out: part[mod][t2][split][128][128]
    float* pbase = part + (size_t)((mod * 16 + t2) * nsplit + split) * 16384;
    #pragma unroll
    for (int a = 0; a < 4; ++a)
        #pragma unroll
        for (int b = 0; b < 4; ++b)
            #pragma unroll
            for (int r = 0; r < 4; ++r) {
                int row = wr + a * 16 + (lane >> 4) * 4 + r;  // C/D: row = quad*4+reg
                int col = wc + b * 16 + r16;                   // col = lane&15
                pbase[row * 128 + col] = acc[a][b][r];
            }
}

// ---------------- K2: split-K reduction + zero head accumulators ----------------
__global__ void reduce_kernel(const float* __restrict__ part, float* __restrict__ P,
                              float* __restrict__ headacc, int nsplit)
{
    int gid = blockIdx.x * 256 + threadIdx.x;   // 786432 total
    if (gid < 1536) headacc[gid] = 0.f;
    int mod = gid >> 18;
    int rem = gid & 262143;
    int b = rem >> 9, j = rem & 511;
    int ti = b >> 7, r = b & 127, tj = j >> 7, c = j & 127;
    int t2 = ti * 4 + tj;
    const float* src = part + (size_t)((mod * 16 + t2) * nsplit) * 16384 + r * 128 + c;
    float s = 0.f;
    for (int k = 0; k < nsplit; ++k) s += src[(size_t)k * 16384];
    P[gid] = s;
}

// ---------------- K3: per-(batch,pair) fused normalize + rank-2 attention + head partials ----------------
__global__ __launch_bounds__(256) void pairs_kernel(
    const float* __restrict__ P, float* __restrict__ headacc,
    const float* __restrict__ W3e, const float* __restrict__ W3m, const float* __restrict__ W3c)
{
    int b = blockIdx.x / 3, pair = blockIdx.x % 3;   // 0:em 1:ec 2:mc
    int t = threadIdx.x;
    __shared__ float2 Pn[256], Qn[256];
    __shared__ float Rinv[256];
    __shared__ float red[4];

    int pm = (pair == 2) ? 1 : 0;
    int qm = (pair == 0) ? 1 : 2;
    const float* prow = P + pm * 262144 + b * 512;
    const float* qrow = P + qm * 262144 + b * 512;

    float px = prow[t], py = prow[256 + t];
    float ip = rsqrtf(px * px + py * py);
    Pn[t] = (float2){px * ip, py * ip};
    float qx = qrow[t], qy = qrow[256 + t];
    float iq = rsqrtf(qx * qx + qy * qy);
    Qn[t] = (float2){qx * iq, qy * iq};
    __syncthreads();

    const float L2E = 1.4426950408889634f;

    // ---- pass R: thread = row r. rowsum + q-weighted row sums -> B-side output (q's feature) ----
    float pxr = Pn[t].x * L2E, pyr = Pn[t].y * L2E;
    float rs = 0.f, rqx = 0.f, rqy = 0.f;
    #pragma unroll 4
    for (int j = 0; j < 256; ++j) {
        float2 qv = Qn[j];
        float x = exp2f(fmaf(pyr, qv.y, pxr * qv.x));
        rs += x;
        rqx = fmaf(qv.x, x, rqx);
        rqy = fmaf(qv.y, x, rqy);
    }
    float rinv = 1.f / rs;
    Rinv[t] = rinv;
    float Fq0 = rqx * rinv, Fq1 = rqy * rinv;

    const float* WR; int hR, offR;
    if (pair == 0)      { WR = W3m; hR = 1; offR = 0; }   // m_feat chunks 0,1
    else if (pair == 1) { WR = W3c; hR = 2; offR = 0; }   // c_feat chunks 0,1
    else                { WR = W3c; hR = 2; offR = 512; } // c_feat chunks 2,3
    float v = Fq0 * WR[offR + t] + Fq1 * WR[offR + 256 + t];
    #pragma unroll
    for (int o = 32; o > 0; o >>= 1) v += __shfl_down(v, o, 64);
    if ((t & 63) == 0) red[t >> 6] = v;
    __syncthreads();
    if (t == 0) atomicAdd(&headacc[b * 3 + hR], red[0] + red[1] + red[2] + red[3]);
    __syncthreads();

    // ---- pass C: thread = col n. col softmax (A-side) or rowsum-prescaled matmul (mc C-form) ----
    float qxr = Qn[t].x * L2E, qyr = Qn[t].y * L2E;
    float cs = 0.f, cpx = 0.f, cpy = 0.f;
    if (pair < 2) {
        #pragma unroll 4
        for (int i = 0; i < 256; ++i) {
            float2 pv = Pn[i];
            float x = exp2f(fmaf(qyr, pv.y, qxr * pv.x));
            cs += x;
            cpx = fmaf(pv.x, x, cpx);
            cpy = fmaf(pv.y, x, cpy);
        }
        float ci = 1.f / cs;
        cpx *= ci; cpy *= ci;
    } else {
        #pragma unroll 4
        for (int i = 0; i < 256; ++i) {
            float2 pv = Pn[i];
            float x = exp2f(fmaf(qyr, pv.y, qxr * pv.x)) * Rinv[i];
            cpx = fmaf(pv.x, x, cpx);
            cpy = fmaf(pv.y, x, cpy);
        }
    }
    const float* WC; int hC, offC;
    if (pair == 0)      { WC = W3e; hC = 0; offC = 0; }   // e_feat chunks 0,1
    else if (pair == 1) { WC = W3e; hC = 0; offC = 512; } // e_feat chunks 2,3
    else                { WC = W3m; hC = 1; offC = 512; } // m_feat chunks 2,3
    float v2 = cpx * WC[offC + t] + cpy * WC[offC + 256 + t];
    #pragma unroll
    for (int o = 32; o > 0; o >>= 1) v2 += __shfl_down(v2, o, 64);
    if ((t & 63) == 0) red[t >> 6] = v2;
    __syncthreads();
    if (t == 0) atomicAdd(&headacc[b * 3 + hC], red[0] + red[1] + red[2] + red[3]);
}

// ---------------- K4: bias + sigmoid ----------------
__global__ void head_kernel(const float* __restrict__ headacc,
                            const float* __restrict__ b3e, const float* __restrict__ b3m,
                            const float* __restrict__ b3c, float* __restrict__ out)
{
    int i = blockIdx.x * 256 + threadIdx.x;
    if (i >= 1536) return;
    int h = i >> 9, b = i & 511;
    float bias = (h == 0) ? b3e[0] : (h == 1) ? b3m[0] : b3c[0];
    float z = headacc[b * 3 + h] + bias;
    out[i] = 1.f / (1.f + __expf(-z));
}

extern "C" void kernel_launch(void* const* d_in, const int* in_sizes, int n_in,
                              void* d_out, int out_size, void* d_ws, size_t ws_size,
                              hipStream_t stream) {
    const float* Ae  = (const float*)d_in[0];
    const float* Am  = (const float*)d_in[1];
    const float* Ac  = (const float*)d_in[2];
    const float* Wex = (const float*)d_in[3];
    const float* Wey = (const float*)d_in[4];
    const float* Wmx = (const float*)d_in[5];
    const float* Wmy = (const float*)d_in[6];
    const float* Wcx = (const float*)d_in[7];
    const float* Wcy = (const float*)d_in[8];
    const float* W3e = (const float*)d_in[9];
    const float* b3e = (const float*)d_in[10];
    const float* W3m = (const float*)d_in[11];
    const float* b3m = (const float*)d_in[12];
    const float* W3c = (const float*)d_in[13];
    const float* b3c = (const float*)d_in[14];

    // workspace: part[48][nsplit][16384] | P[786432] | headacc[1536]
    size_t fixed = (size_t)786432 * 4 + 1536 * 4;
    int nsplit = 2;
    if (ws_size > fixed) {
        size_t avail = (ws_size - fixed) / ((size_t)48 * 16384 * 4);
        nsplit = (avail < MAXSPLIT) ? (int)avail : MAXSPLIT;
        if (nsplit < 1) nsplit = 1;
    }

    float* part    = (float*)d_ws;
    float* P       = part + (size_t)48 * nsplit * 16384;
    float* headacc = P + 786432;

    gemm_kernel<<<48 * nsplit, 256, 0, stream>>>(Ae, Am, Ac, Wex, Wey, Wmx, Wmy, Wcx, Wcy,
                                                 part, nsplit);
    reduce_kernel<<<3072, 256, 0, stream>>>(part, P, headacc, nsplit);
    pairs_kernel<<<1536, 256, 0, stream>>>(P, headacc, W3e, W3m, W3c);
    head_kernel<<<6, 256, 0, stream>>>(headacc, b3e, b3m, b3c, (float*)d_out);
}

// Round 4
// 354.124 us; speedup vs baseline: 1.4132x; 1.1982x over previous
//
#include <hip/hip_runtime.h>
#include <hip/hip_bf16.h>

typedef short short8 __attribute__((ext_vector_type(8)));
typedef float float4v __attribute__((ext_vector_type(4)));

#define TK 32
#define MAXSPLIT 16
#define APAD 40   // 80 B row stride for bf16 A tile: conflict-free-ish, 16B-aligned frag reads

typedef const __attribute__((address_space(1))) void* gas_ptr;
typedef __attribute__((address_space(3))) void* las_ptr;

__device__ __forceinline__ void dma16(const float* g, float* l) {
    // async global->LDS DMA, 16 B per lane; LDS dest = wave-uniform base + lane*16
    __builtin_amdgcn_global_load_lds((gas_ptr)g, (las_ptr)l, 16, 0, 0);
}

__device__ __forceinline__ unsigned int bfrne(float f) {
    unsigned int u = __builtin_bit_cast(unsigned int, f);
    return (u + 0x7fffu + ((u >> 16) & 1u)) >> 16;   // RNE
}
__device__ __forceinline__ unsigned int pack2bf(float a, float b) {
    return bfrne(a) | (bfrne(b) << 16);
}

// ---------------- K1: split-K bf16 MFMA GEMM: P_mod[b][j] = sum_k A[b,k] * W[j,k] ----------------
// 128x128 tiles, 4 waves of 64x64, BK=32.
// A: coalesced global_load_dwordx4 -> cvt bf16 -> padded LDS (store point after MFMAs).
// B: global_load_lds fp32 DMA, XOR-granule swizzle, double-buffered, fire-and-forget.
__global__ __launch_bounds__(256, 3) void gemm_kernel(
    const float* __restrict__ Ae, const float* __restrict__ Am, const float* __restrict__ Ac,
    const float* __restrict__ Wex, const float* __restrict__ Wey,
    const float* __restrict__ Wmx, const float* __restrict__ Wmy,
    const float* __restrict__ Wcx, const float* __restrict__ Wcy,
    float* __restrict__ part, int nsplit)
{
    // XCD grouping: xcd = bid&7 gets a contiguous job range -> 16-tile (mod,split) groups
    // co-resident on one XCD for L2 slab reuse.
    int nb = gridDim.x;                 // 48*nsplit, divisible by 8
    int per = nb >> 3;
    int bid = blockIdx.x;
    int job = (bid & 7) * per + (bid >> 3);

    int mod = job / (16 * nsplit);
    int rem = job - mod * 16 * nsplit;
    int split = rem >> 4;
    int t2 = rem & 15;
    int ti = t2 >> 2, tj = t2 & 3;

    const float* A; const float* Wx; const float* Wy; int K;
    if (mod == 0)      { A = Ae; Wx = Wex; Wy = Wey; K = 20000; }
    else if (mod == 1) { A = Am; Wx = Wmx; Wy = Wmy; K = 15000; }
    else               { A = Ac; Wx = Wcx; Wy = Wcy; K = 20000; }

    int chunk = ((K + nsplit * TK - 1) / (nsplit * TK)) * TK;
    int kstart = split * chunk;
    int kend = kstart + chunk; if (kend > K) kend = K;
    int nstep = (kend - kstart + TK - 1) / TK;

    const float* Abase = A + (size_t)(ti * 128) * K;
    const float* Wbase = (tj < 2) ? (Wx + (size_t)(tj * 128) * K)
                                  : (Wy + (size_t)((tj - 2) * 128) * K);

    __shared__ unsigned short As[2][128][APAD];   // bf16, padded
    __shared__ float Bs[2][128 * 32];             // fp32, linear (DMA target), granule-swizzled

    int tid = threadIdx.x;
    int lane = tid & 63, w = tid >> 6;
    int wr = (w >> 1) * 64, wc = (w & 1) * 64;
    int q = lane >> 4, r16 = lane & 15, q8 = q * 8;

    // A staging: inst i covers rows i*32 + tid>>3, col granule (tid&7)*4  (full 128B lines / 8 lanes)
    int ra0 = tid >> 3;
    int ca  = (tid & 7) * 4;
    // B DMA: chunk c = i*4+w (1 KB = 8 rows), lane -> row c*8 + (lane>>3), phys granule lane&7
    int lrow = lane >> 3, l8 = lane & 7;

    float4v ar[4];
    auto loadA = [&](int k0) {
        int k = k0 + ca; if (k > K - 4) k = K - 4;       // clamp; tail zeroed at store
        #pragma unroll
        for (int i = 0; i < 4; ++i)
            ar[i] = *(const float4v*)(Abase + (size_t)(ra0 + i * 32) * K + k);
    };
    auto storeA = [&](int buf, int k0, bool tail) {
        bool kill = tail && (k0 + ca >= kend);
        #pragma unroll
        for (int i = 0; i < 4; ++i) {
            float4v v = ar[i];
            if (kill) v = (float4v){0.f, 0.f, 0.f, 0.f};
            uint2 pk;
            pk.x = pack2bf(v[0], v[1]);
            pk.y = pack2bf(v[2], v[3]);
            *(uint2*)&As[buf][ra0 + i * 32][ca] = pk;
        }
    };
    auto dmaB = [&](int buf, int k0) {
        float* base = &Bs[buf][0];
        #pragma unroll
        for (int i = 0; i < 4; ++i) {
            int c = i * 4 + w;
            int r = c * 8 + lrow;
            int g = l8 ^ (r & 7);                        // logical granule for this phys slot
            int k = k0 + g * 4; if (k > K - 4) k = K - 4;
            dma16(Wbase + (size_t)r * K + k, base + c * 256);
        }
    };

    float4v acc[4][4];
    #pragma unroll
    for (int a = 0; a < 4; ++a)
        #pragma unroll
        for (int b = 0; b < 4; ++b)
            acc[a][b] = (float4v){0.f, 0.f, 0.f, 0.f};

    auto computeStep = [&](int buf, int k0, bool tail) {
        short8 fa[4], fb[4];
        #pragma unroll
        for (int a = 0; a < 4; ++a)
            fa[a] = *(const short8*)&As[buf][wr + a * 16 + r16][q8];
        #pragma unroll
        for (int b = 0; b < 4; ++b) {
            int r = wc + b * 16 + r16;
            int rx = r & 7;
            const float* rowp = &Bs[buf][r * 32];
            float4v g0 = *(const float4v*)(rowp + (((2 * q)     ^ rx) * 4));
            float4v g1 = *(const float4v*)(rowp + (((2 * q + 1) ^ rx) * 4));
            if (tail) {
                if (k0 + q8 >= kend)     g0 = (float4v){0.f, 0.f, 0.f, 0.f};
                if (k0 + q8 + 4 >= kend) g1 = (float4v){0.f, 0.f, 0.f, 0.f};
            }
            union { unsigned int u[4]; short8 s; } pk;
            pk.u[0] = pack2bf(g0[0], g0[1]);
            pk.u[1] = pack2bf(g0[2], g0[3]);
            pk.u[2] = pack2bf(g1[0], g1[1]);
            pk.u[3] = pack2bf(g1[2], g1[3]);
            fb[b] = pk.s;
        }
        #pragma unroll
        for (int a = 0; a < 4; ++a)
            #pragma unroll
            for (int b = 0; b < 4; ++b)
                acc[a][b] = __builtin_amdgcn_mfma_f32_16x16x32_bf16(fa[a], fb[b], acc[a][b], 0, 0, 0);
    };

    // prologue: stage step 0
    loadA(kstart);
    dmaB(0, kstart);
    storeA(0, kstart, kstart + TK > kend);

    for (int s = 0; s < nstep; ++s) {
        int cur = s & 1;
        int k0 = kstart + s * TK;
        int k1 = k0 + TK;
        bool more = (s + 1 < nstep);
        __syncthreads();                 // buf[cur] ready (vm+lgkm drained); all reads of cur^1 done
        if (more) { dmaB(cur ^ 1, k1); loadA(k1); }   // prefetch window = compute + storeA
        computeStep(cur, k0, k1 > kend);
        if (more) storeA(cur ^ 1, k1, k1 + TK > kend);
    }

    // partial tile out: part[mod][t2][split][128][128]
    float* pbase = part + (size_t)((mod * 16 + t2) * nsplit + split) * 16384;
    #pragma unroll
    for (int a = 0; a < 4; ++a)
        #pragma unroll
        for (int b = 0; b < 4; ++b)
            #pragma unroll
            for (int r = 0; r < 4; ++r) {
                int row = wr + a * 16 + (lane >> 4) * 4 + r;  // C/D: row = quad*4+reg
                int col = wc + b * 16 + r16;                   // col = lane&15
                pbase[row * 128 + col] = acc[a][b][r];
            }
}

// ---------------- K2: split-K reduction + zero head accumulators ----------------
__global__ void reduce_kernel(const float* __restrict__ part, float* __restrict__ P,
                              float* __restrict__ headacc, int nsplit)
{
    int gid = blockIdx.x * 256 + threadIdx.x;   // 786432 total
    if (gid < 1536) headacc[gid] = 0.f;
    int mod = gid >> 18;
    int rem = gid & 262143;
    int b = rem >> 9, j = rem & 511;
    int ti = b >> 7, r = b & 127, tj = j >> 7, c = j & 127;
    int t2 = ti * 4 + tj;
    const float* src = part + (size_t)((mod * 16 + t2) * nsplit) * 16384 + r * 128 + c;
    float s = 0.f;
    for (int k = 0; k < nsplit; ++k) s += src[(size_t)k * 16384];
    P[gid] = s;
}

// ---------------- K3: per-(batch,pair) fused normalize + rank-2 attention + head partials ----------------
__global__ __launch_bounds__(256) void pairs_kernel(
    const float* __restrict__ P, float* __restrict__ headacc,
    const float* __restrict__ W3e, const float* __restrict__ W3m, const float* __restrict__ W3c)
{
    int b = blockIdx.x / 3, pair = blockIdx.x % 3;   // 0:em 1:ec 2:mc
    int t = threadIdx.x;
    __shared__ float2 Pn[256], Qn[256];
    __shared__ float Rinv[256];
    __shared__ float red[4];

    int pm = (pair == 2) ? 1 : 0;
    int qm = (pair == 0) ? 1 : 2;
    const float* prow = P + pm * 262144 + b * 512;
    const float* qrow = P + qm * 262144 + b * 512;

    float px = prow[t], py = prow[256 + t];
    float ip = rsqrtf(px * px + py * py);
    Pn[t] = (float2){px * ip, py * ip};
    float qx = qrow[t], qy = qrow[256 + t];
    float iq = rsqrtf(qx * qx + qy * qy);
    Qn[t] = (float2){qx * iq, qy * iq};
    __syncthreads();

    const float L2E = 1.4426950408889634f;

    // ---- pass R: thread = row r. rowsum + q-weighted row sums -> B-side output (q's feature) ----
    float pxr = Pn[t].x * L2E, pyr = Pn[t].y * L2E;
    float rs = 0.f, rqx = 0.f, rqy = 0.f;
    #pragma unroll 4
    for (int j = 0; j < 256; ++j) {
        float2 qv = Qn[j];
        float x = exp2f(fmaf(pyr, qv.y, pxr * qv.x));
        rs += x;
        rqx = fmaf(qv.x, x, rqx);
        rqy = fmaf(qv.y, x, rqy);
    }
    float rinv = 1.f / rs;
    Rinv[t] = rinv;
    float Fq0 = rqx * rinv, Fq1 = rqy * rinv;

    const float* WR; int hR, offR;
    if (pair == 0)      { WR = W3m; hR = 1; offR = 0; }   // m_feat chunks 0,1
    else if (pair == 1) { WR = W3c; hR = 2; offR = 0; }   // c_feat chunks 0,1
    else                { WR = W3c; hR = 2; offR = 512; } // c_feat chunks 2,3
    float v = Fq0 * WR[offR + t] + Fq1 * WR[offR + 256 + t];
    #pragma unroll
    for (int o = 32; o > 0; o >>= 1) v += __shfl_down(v, o, 64);
    if ((t & 63) == 0) red[t >> 6] = v;
    __syncthreads();
    if (t == 0) atomicAdd(&headacc[b * 3 + hR], red[0] + red[1] + red[2] + red[3]);
    __syncthreads();

    // ---- pass C: thread = col n. col softmax (A-side) or rowsum-prescaled matmul (mc C-form) ----
    float qxr = Qn[t].x * L2E, qyr = Qn[t].y * L2E;
    float cs = 0.f, cpx = 0.f, cpy = 0.f;
    if (pair < 2) {
        #pragma unroll 4
        for (int i = 0; i < 256; ++i) {
            float2 pv = Pn[i];
            float x = exp2f(fmaf(qyr, pv.y, qxr * pv.x));
            cs += x;
            cpx = fmaf(pv.x, x, cpx);
            cpy = fmaf(pv.y, x, cpy);
        }
        float ci = 1.f / cs;
        cpx *= ci; cpy *= ci;
    } else {
        #pragma unroll 4
        for (int i = 0; i < 256; ++i) {
            float2 pv = Pn[i];
            float x = exp2f(fmaf(qyr, pv.y, qxr * pv.x)) * Rinv[i];
            cpx = fmaf(pv.x, x, cpx);
            cpy = fmaf(pv.y, x, cpy);
        }
    }
    const float* WC; int hC, offC;
    if (pair == 0)      { WC = W3e; hC = 0; offC = 0; }   // e_feat chunks 0,1
    else if (pair == 1) { WC = W3e; hC = 0; offC = 512; } // e_feat chunks 2,3
    else                { WC = W3m; hC = 1; offC = 512; } // m_feat chunks 2,3
    float v2 = cpx * WC[offC + t] + cpy * WC[offC + 256 + t];
    #pragma unroll
    for (int o = 32; o > 0; o >>= 1) v2 += __shfl_down(v2, o, 64);
    if ((t & 63) == 0) red[t >> 6] = v2;
    __syncthreads();
    if (t == 0) atomicAdd(&headacc[b * 3 + hC], red[0] + red[1] + red[2] + red[3]);
}

// ---------------- K4: bias + sigmoid ----------------
__global__ void head_kernel(const float* __restrict__ headacc,
                            const float* __restrict__ b3e, const float* __restrict__ b3m,
                            const float* __restrict__ b3c, float* __restrict__ out)
{
    int i = blockIdx.x * 256 + threadIdx.x;
    if (i >= 1536) return;
    int h = i >> 9, b = i & 511;
    float bias = (h == 0) ? b3e[0] : (h == 1) ? b3m[0] : b3c[0];
    float z = headacc[b * 3 + h] + bias;
    out[i] = 1.f / (1.f + __expf(-z));
}

extern "C" void kernel_launch(void* const* d_in, const int* in_sizes, int n_in,
                              void* d_out, int out_size, void* d_ws, size_t ws_size,
                              hipStream_t stream) {
    const float* Ae  = (const float*)d_in[0];
    const float* Am  = (const float*)d_in[1];
    const float* Ac  = (const float*)d_in[2];
    const float* Wex = (const float*)d_in[3];
    const float* Wey = (const float*)d_in[4];
    const float* Wmx = (const float*)d_in[5];
    const float* Wmy = (const float*)d_in[6];
    const float* Wcx = (const float*)d_in[7];
    const float* Wcy = (const float*)d_in[8];
    const float* W3e = (const float*)d_in[9];
    const float* b3e = (const float*)d_in[10];
    const float* W3m = (const float*)d_in[11];
    const float* b3m = (const float*)d_in[12];
    const float* W3c = (const float*)d_in[13];
    const float* b3c = (const float*)d_in[14];

    // workspace: part[48][nsplit][16384] | P[786432] | headacc[1536]
    size_t fixed = (size_t)786432 * 4 + 1536 * 4;
    int nsplit = 2;
    if (ws_size > fixed) {
        size_t avail = (ws_size - fixed) / ((size_t)48 * 16384 * 4);
        nsplit = (avail < MAXSPLIT) ? (int)avail : MAXSPLIT;
        if (nsplit < 1) nsplit = 1;
    }

    float* part    = (float*)d_ws;
    float* P       = part + (size_t)48 * nsplit * 16384;
    float* headacc = P + 786432;

    gemm_kernel<<<48 * nsplit, 256, 0, stream>>>(Ae, Am, Ac, Wex, Wey, Wmx, Wmy, Wcx, Wcy,
                                                 part, nsplit);
    reduce_kernel<<<3072, 256, 0, stream>>>(part, P, headacc, nsplit);
    pairs_kernel<<<1536, 256, 0, stream>>>(P, headacc, W3e, W3m, W3c);
    head_kernel<<<6, 256, 0, stream>>>(headacc, b3e, b3m, b3c, (float*)d_out);
}